// Round 1
// baseline (220.799 us; speedup 1.0000x reference)
//
#include <hip/hip_runtime.h>
#include <stdint.h>

// ---------------------------------------------------------------------------
// Fused RBF histogram:  hist[o,i] = sum_n exp(-||x_n - c_o||^2 / 2) * x[n,i]
// N=524288, IN=64, OUT=128.  fp32 in/out.
//
// Strategy: bf16 MFMA (16x16x32) with hi/lo split compensation for the
// distance GEMM (bf16 alone gives ~2.5% exp error > 2% threshold; the 3-term
// split leaves ~1e-5).  Second GEMM (rbf^T @ x) in plain bf16 (~0.3% err).
// Accumulator pre-init with -(x2+c2)/2 so rbf = exp(acc) directly.
// Per-block partial [128x64] kept in MFMA accumulators across 16 row-tiles,
// atomically added to d_out at the end (d_out zeroed by zero_out_kernel).
// ---------------------------------------------------------------------------

typedef __bf16 bf16x8 __attribute__((ext_vector_type(8)));
typedef unsigned short ushortx8 __attribute__((ext_vector_type(8)));
typedef unsigned short ushortx4 __attribute__((ext_vector_type(4)));
typedef float floatx4 __attribute__((ext_vector_type(4)));

#define LOG2E 1.4426950408889634f

#if __has_builtin(__builtin_amdgcn_exp2f)
#define EXP2F(x) __builtin_amdgcn_exp2f(x)
#else
#define EXP2F(x) exp2f(x)
#endif

// round-to-nearest-even fp32 -> bf16 (bit trick; no NaN inputs here)
static __device__ __forceinline__ unsigned short f2bf(float f) {
  unsigned int u = __float_as_uint(f);
  u += 0x7fffu + ((u >> 16) & 1u);
  return (unsigned short)(u >> 16);
}
static __device__ __forceinline__ float bf2f(unsigned short h) {
  return __uint_as_float(((unsigned int)h) << 16);
}

static __device__ __forceinline__ floatx4 mfma_bf16(ushortx8 a, ushortx8 b, floatx4 c) {
  return __builtin_amdgcn_mfma_f32_16x16x32_bf16(
      __builtin_bit_cast(bf16x8, a), __builtin_bit_cast(bf16x8, b), c, 0, 0, 0);
}

// LDS row stride 72 bf16 = 144 B: multiple of 16 (ds_read_b128-aligned) and
// bank-stride 4 -> b128 frag reads are only 2-way conflicted (free, m136).
#define LSTR 72

__global__ __launch_bounds__(256, 2) void rbf_hist_kernel(
    const float* __restrict__ x, const float* __restrict__ c,
    float* __restrict__ out) {
  __shared__ unsigned short sXhi[64][LSTR];  // x tile, bf16 hi  [n][i]
  __shared__ unsigned short sXlo[64][LSTR];  // x tile, bf16 lo  [n][i]
  __shared__ unsigned short sXT [64][LSTR];  // x tile, bf16 hi, transposed [i][n]
  __shared__ unsigned short sP  [128][LSTR]; // rbf tile, bf16   [o][n]
  __shared__ float          sX2 [64];        // exact fp32 ||x_n||^2

  const int t    = threadIdx.x;
  const int lane = t & 63;
  const int w    = t >> 6;      // wave 0..3
  const int l15  = lane & 15;
  const int quad = lane >> 4;

  // ---- one-time: c fragments (hi/lo) + exact c2, all in registers ----
  // B-frag for stage A: B[k=i][n=o]: lane reads c[ot*16+l15][32s+quad*8 .. +7]
  ushortx8 chi[8][2], clo[8][2];
  float c2r[8];
#pragma unroll
  for (int ot = 0; ot < 8; ++ot) {
    float sq = 0.f;
#pragma unroll
    for (int s = 0; s < 2; ++s) {
      const float* p = c + (ot * 16 + l15) * 64 + s * 32 + quad * 8;
      float4 va = *(const float4*)(p);
      float4 vb = *(const float4*)(p + 4);
      float f[8] = {va.x, va.y, va.z, va.w, vb.x, vb.y, vb.z, vb.w};
      ushortx8 hv, lv;
#pragma unroll
      for (int j = 0; j < 8; ++j) {
        sq += f[j] * f[j];
        unsigned short hh = f2bf(f[j]);
        hv[j] = hh;
        lv[j] = f2bf(f[j] - bf2f(hh));  // exact split: f = hi + lo + O(2^-18)
      }
      chi[ot][s] = hv;
      clo[ot][s] = lv;
    }
    // full-row c2: sum partials across the 4 quads (lanes l15, l15+16, +32, +48)
    sq += __shfl_xor(sq, 16);
    sq += __shfl_xor(sq, 32);
    c2r[ot] = sq;
  }

  // persistent histogram accumulators: wave w owns o-tiles {2w, 2w+1} x 4 i-tiles
  floatx4 hacc[2][4];
#pragma unroll
  for (int a = 0; a < 2; ++a)
#pragma unroll
    for (int b = 0; b < 4; ++b) {
      floatx4 z = {0.f, 0.f, 0.f, 0.f};
      hacc[a][b] = z;
    }

  const int row_block = blockIdx.x * 1024;  // 512 blocks * 1024 rows = N

  // register prefetch of first x tile: thread t -> row r=t>>2, cols q*4+g*16
  const int r = t >> 2, q = t & 3;
  float4 v[4];
#pragma unroll
  for (int g = 0; g < 4; ++g)
    v[g] = *(const float4*)(x + (size_t)(row_block + r) * 64 + q * 4 + g * 16);

  for (int it = 0; it < 16; ++it) {
    __syncthreads();  // prev iteration's stage B done -> LDS buffers free

    // ---- staging: convert prefetched regs -> LDS hi/lo/xT + exact x2 ----
    {
      float sq = 0.f;
#pragma unroll
      for (int g = 0; g < 4; ++g) {
        const int col = q * 4 + g * 16;
        float f[4] = {v[g].x, v[g].y, v[g].z, v[g].w};
        ushortx4 hv, lv;
#pragma unroll
        for (int j = 0; j < 4; ++j) {
          sq += f[j] * f[j];
          unsigned short hh = f2bf(f[j]);
          hv[j] = hh;
          lv[j] = f2bf(f[j] - bf2f(hh));
          sXT[col + j][r] = hh;  // transposed copy for stage-B B-frags
        }
        *(ushortx4*)&sXhi[r][col] = hv;
        *(ushortx4*)&sXlo[r][col] = lv;
      }
      sq += __shfl_xor(sq, 1);   // reduce over the 4 threads sharing row r
      sq += __shfl_xor(sq, 2);
      if (q == 0) sX2[r] = sq;
    }
    __syncthreads();  // x tile ready

    // issue next tile's global loads now; latency hides under stages A+B
    if (it < 15) {
      const size_t nrow = (size_t)(row_block + (it + 1) * 64 + r) * 64;
#pragma unroll
      for (int g = 0; g < 4; ++g)
        v[g] = *(const float4*)(x + nrow + q * 4 + g * 16);
    }

    // ---- stage A: scores. wave w owns n-tile w (16 rows) x all 8 o-tiles ----
    {
      const int nt = w;
      ushortx8 xh[2], xl[2];
#pragma unroll
      for (int s = 0; s < 2; ++s) {
        xh[s] = *(const ushortx8*)&sXhi[nt * 16 + l15][s * 32 + quad * 8];
        xl[s] = *(const ushortx8*)&sXlo[nt * 16 + l15][s * 32 + quad * 8];
      }
      float x2v[4];
#pragma unroll
      for (int e = 0; e < 4; ++e) x2v[e] = sX2[nt * 16 + quad * 4 + e];

#pragma unroll
      for (int ot = 0; ot < 8; ++ot) {
        floatx4 acc;
#pragma unroll
        for (int e = 0; e < 4; ++e) acc[e] = -0.5f * (x2v[e] + c2r[ot]);
        // xc = hi*hi + hi*lo + lo*hi  (3-term split; lo*lo ~1e-5, dropped)
        acc = mfma_bf16(xh[0], chi[ot][0], acc);
        acc = mfma_bf16(xh[1], chi[ot][1], acc);
        acc = mfma_bf16(xh[0], clo[ot][0], acc);
        acc = mfma_bf16(xh[1], clo[ot][1], acc);
        acc = mfma_bf16(xl[0], chi[ot][0], acc);
        acc = mfma_bf16(xl[1], chi[ot][1], acc);
        // rbf = exp(acc); write bf16 to P[o][n] (C/D: o=l15+16ot, n=16nt+4quad+e)
        unsigned short rb[4];
#pragma unroll
        for (int e = 0; e < 4; ++e) rb[e] = f2bf(EXP2F(acc[e] * LOG2E));
        const int o = ot * 16 + l15;
        const int n0 = nt * 16 + quad * 4;
        *(unsigned int*)&sP[o][n0]     = (unsigned int)rb[0] | ((unsigned int)rb[1] << 16);
        *(unsigned int*)&sP[o][n0 + 2] = (unsigned int)rb[2] | ((unsigned int)rb[3] << 16);
      }
    }
    __syncthreads();  // P ready

    // ---- stage B: hist += P^T-style GEMM. A=P[o][n], B=xT[i][n], K=n(64) ----
#pragma unroll
    for (int s = 0; s < 2; ++s) {
      ushortx8 a0 = *(const ushortx8*)&sP[(2 * w)     * 16 + l15][s * 32 + quad * 8];
      ushortx8 a1 = *(const ushortx8*)&sP[(2 * w + 1) * 16 + l15][s * 32 + quad * 8];
#pragma unroll
      for (int itl = 0; itl < 4; ++itl) {
        ushortx8 b = *(const ushortx8*)&sXT[itl * 16 + l15][s * 32 + quad * 8];
        hacc[0][itl] = mfma_bf16(a0, b, hacc[0][itl]);
        hacc[1][itl] = mfma_bf16(a1, b, hacc[1][itl]);
      }
    }
  }

  // ---- epilogue: one atomic per owned output element ----
  // D layout: i (cols) = itl*16 + l15, o (rows) = (2w+oi)*16 + quad*4 + e
#pragma unroll
  for (int oi = 0; oi < 2; ++oi)
#pragma unroll
    for (int itl = 0; itl < 4; ++itl)
#pragma unroll
      for (int e = 0; e < 4; ++e) {
        int o = (2 * w + oi) * 16 + quad * 4 + e;
        int i = itl * 16 + l15;
        atomicAdd(out + o * 64 + i, hacc[oi][itl][e]);
      }
}

__global__ void zero_out_kernel(float* out, int n) {
  int i = blockIdx.x * 256 + threadIdx.x;
  if (i < n) out[i] = 0.f;
}

extern "C" void kernel_launch(void* const* d_in, const int* in_sizes, int n_in,
                              void* d_out, int out_size, void* d_ws, size_t ws_size,
                              hipStream_t stream) {
  (void)in_sizes; (void)n_in; (void)d_ws; (void)ws_size;
  const float* x = (const float*)d_in[0];        // [524288, 64]
  const float* c = (const float*)d_in[1];        // [128, 64]
  float* out = (float*)d_out;                    // [128, 64]

  zero_out_kernel<<<(out_size + 255) / 256, 256, 0, stream>>>(out, out_size);
  rbf_hist_kernel<<<512, 256, 0, stream>>>(x, c, out);
}

// Round 2
// 213.648 us; speedup vs baseline: 1.0335x; 1.0335x over previous
//
#include <hip/hip_runtime.h>
#include <stdint.h>

// ---------------------------------------------------------------------------
// Fused RBF histogram:  hist[o,i] = sum_n exp(-||x_n - c_o||^2 / 2) * x[n,i]
// N=524288, IN=64, OUT=128.  fp32 in/out.
//
// R2 changes vs R1 (81us, Occ 19%):
//  - stage A wave-ownership: wave owns 2 o-tiles (c-frags 32 VGPRs, was 128)
//    and loops all 4 n-tiles; total regs ~130 -> 3 blocks/CU (was 2).
//  - grid 768 = 3 blocks/CU exact residency, grid-stride over 8192 row-tiles.
//  - epilogue: plain-store per-block partials to d_ws + reduce kernel
//    (was 4.2M device-scope atomics -> 32MB of HBM RMW traffic).
// ---------------------------------------------------------------------------

typedef __bf16 bf16x8 __attribute__((ext_vector_type(8)));
typedef unsigned short ushortx8 __attribute__((ext_vector_type(8)));
typedef unsigned short ushortx4 __attribute__((ext_vector_type(4)));
typedef float floatx4 __attribute__((ext_vector_type(4)));

#define LOG2E 1.4426950408889634f
#define GRIDN 768      // 3 blocks/CU x 256 CUs
#define NTILES 8192    // 524288 / 64

#if __has_builtin(__builtin_amdgcn_exp2f)
#define EXP2F(x) __builtin_amdgcn_exp2f(x)
#else
#define EXP2F(x) exp2f(x)
#endif

// round-to-nearest-even fp32 -> bf16 (bit trick; no NaN inputs here)
static __device__ __forceinline__ unsigned short f2bf(float f) {
  unsigned int u = __float_as_uint(f);
  u += 0x7fffu + ((u >> 16) & 1u);
  return (unsigned short)(u >> 16);
}
static __device__ __forceinline__ float bf2f(unsigned short h) {
  return __uint_as_float(((unsigned int)h) << 16);
}

static __device__ __forceinline__ floatx4 mfma_bf16(ushortx8 a, ushortx8 b, floatx4 c) {
  return __builtin_amdgcn_mfma_f32_16x16x32_bf16(
      __builtin_bit_cast(bf16x8, a), __builtin_bit_cast(bf16x8, b), c, 0, 0, 0);
}

// LDS row stride 72 bf16 = 144 B: multiple of 16 (ds_read_b128-aligned) and
// bank-stride 4 -> b128 frag reads are at worst 2-way conflicted (free, m136).
#define LSTR 72

__global__ __launch_bounds__(256, 3) void rbf_hist_kernel(
    const float* __restrict__ x, const float* __restrict__ c,
    float* __restrict__ out, float* __restrict__ ws, int use_ws) {
  __shared__ unsigned short sXhi[64][LSTR];  // x tile, bf16 hi  [n][i]
  __shared__ unsigned short sXlo[64][LSTR];  // x tile, bf16 lo  [n][i]
  __shared__ unsigned short sXT [64][LSTR];  // x tile, bf16 hi, transposed [i][n]
  __shared__ unsigned short sP  [128][LSTR]; // rbf tile, bf16   [o][n]
  __shared__ float          sX2 [64];        // exact fp32 ||x_n||^2

  const int t    = threadIdx.x;
  const int lane = t & 63;
  const int w    = t >> 6;      // wave 0..3; owns o-tiles {2w, 2w+1}
  const int l15  = lane & 15;
  const int quad = lane >> 4;

  // ---- one-time: c fragments (hi/lo) for this wave's 2 o-tiles + exact c2 ----
  // B-frag for stage A: B[k=i][n=o]: lane reads c[ot*16+l15][32s+quad*8 .. +7]
  ushortx8 chi[2][2], clo[2][2];
  float c2r[2];
#pragma unroll
  for (int oo = 0; oo < 2; ++oo) {
    const int ot = 2 * w + oo;
    float sq = 0.f;
#pragma unroll
    for (int s = 0; s < 2; ++s) {
      const float* p = c + (ot * 16 + l15) * 64 + s * 32 + quad * 8;
      float4 va = *(const float4*)(p);
      float4 vb = *(const float4*)(p + 4);
      float f[8] = {va.x, va.y, va.z, va.w, vb.x, vb.y, vb.z, vb.w};
      ushortx8 hv, lv;
#pragma unroll
      for (int j = 0; j < 8; ++j) {
        sq += f[j] * f[j];
        unsigned short hh = f2bf(f[j]);
        hv[j] = hh;
        lv[j] = f2bf(f[j] - bf2f(hh));  // exact split: f = hi + lo + O(2^-18)
      }
      chi[oo][s] = hv;
      clo[oo][s] = lv;
    }
    // full-row c2: sum partials across the 4 quads
    sq += __shfl_xor(sq, 16);
    sq += __shfl_xor(sq, 32);
    c2r[oo] = sq;
  }

  // persistent histogram accumulators: wave w owns o-tiles {2w, 2w+1} x 4 i-tiles
  floatx4 hacc[2][4];
#pragma unroll
  for (int a = 0; a < 2; ++a)
#pragma unroll
    for (int b = 0; b < 4; ++b) {
      floatx4 z = {0.f, 0.f, 0.f, 0.f};
      hacc[a][b] = z;
    }

  // register prefetch of first x tile: thread t -> row r=t>>2, cols q*4+g*16
  const int r = t >> 2, q = t & 3;
  float4 v[4];
  {
    const size_t row0 = (size_t)(blockIdx.x * 64 + r) * 64;
#pragma unroll
    for (int g = 0; g < 4; ++g)
      v[g] = *(const float4*)(x + row0 + q * 4 + g * 16);
  }

  for (int tile = blockIdx.x; tile < NTILES; tile += GRIDN) {
    __syncthreads();  // prev iteration's stage B done -> LDS buffers free

    // ---- staging: convert prefetched regs -> LDS hi/lo/xT + exact x2 ----
    {
      float sq = 0.f;
#pragma unroll
      for (int g = 0; g < 4; ++g) {
        const int col = q * 4 + g * 16;
        float f[4] = {v[g].x, v[g].y, v[g].z, v[g].w};
        ushortx4 hv, lv;
#pragma unroll
        for (int j = 0; j < 4; ++j) {
          sq += f[j] * f[j];
          unsigned short hh = f2bf(f[j]);
          hv[j] = hh;
          lv[j] = f2bf(f[j] - bf2f(hh));
          sXT[col + j][r] = hh;  // transposed copy for stage-B B-frags
        }
        *(ushortx4*)&sXhi[r][col] = hv;
        *(ushortx4*)&sXlo[r][col] = lv;
      }
      sq += __shfl_xor(sq, 1);   // reduce over the 4 threads sharing row r
      sq += __shfl_xor(sq, 2);
      if (q == 0) sX2[r] = sq;
    }

    // issue next tile's global loads now; latency hides under stages A+B
    if (tile + GRIDN < NTILES) {
      const size_t nrow = (size_t)((tile + GRIDN) * 64 + r) * 64;
#pragma unroll
      for (int g = 0; g < 4; ++g)
        v[g] = *(const float4*)(x + nrow + q * 4 + g * 16);
    }
    __syncthreads();  // x tile ready

    // ---- stage A: scores. wave w: o-tiles {2w,2w+1} x all 4 n-tiles ----
#pragma unroll
    for (int nt = 0; nt < 4; ++nt) {
      ushortx8 xh0 = *(const ushortx8*)&sXhi[nt * 16 + l15][quad * 8];
      ushortx8 xh1 = *(const ushortx8*)&sXhi[nt * 16 + l15][32 + quad * 8];
      ushortx8 xl0 = *(const ushortx8*)&sXlo[nt * 16 + l15][quad * 8];
      ushortx8 xl1 = *(const ushortx8*)&sXlo[nt * 16 + l15][32 + quad * 8];
      float x2v[4];
#pragma unroll
      for (int e = 0; e < 4; ++e) x2v[e] = sX2[nt * 16 + quad * 4 + e];

#pragma unroll
      for (int oo = 0; oo < 2; ++oo) {
        floatx4 acc;
#pragma unroll
        for (int e = 0; e < 4; ++e) acc[e] = -0.5f * (x2v[e] + c2r[oo]);
        // xc = hi*hi + hi*lo + lo*hi  (3-term split; lo*lo ~1e-5, dropped)
        acc = mfma_bf16(xh0, chi[oo][0], acc);
        acc = mfma_bf16(xh1, chi[oo][1], acc);
        acc = mfma_bf16(xh0, clo[oo][0], acc);
        acc = mfma_bf16(xh1, clo[oo][1], acc);
        acc = mfma_bf16(xl0, chi[oo][0], acc);
        acc = mfma_bf16(xl1, chi[oo][1], acc);
        // rbf = exp(acc); write bf16 to P[o][n] (C/D: o-col=l15, n-row=quad*4+e)
        unsigned short rb[4];
#pragma unroll
        for (int e = 0; e < 4; ++e) rb[e] = f2bf(EXP2F(acc[e] * LOG2E));
        const int o = (2 * w + oo) * 16 + l15;
        const int n0 = nt * 16 + quad * 4;
        *(unsigned int*)&sP[o][n0]     = (unsigned int)rb[0] | ((unsigned int)rb[1] << 16);
        *(unsigned int*)&sP[o][n0 + 2] = (unsigned int)rb[2] | ((unsigned int)rb[3] << 16);
      }
    }
    __syncthreads();  // P ready

    // ---- stage B: hist += GEMM. A=P[o][n], B=xT[i][n], K=n(64) ----
#pragma unroll
    for (int s = 0; s < 2; ++s) {
      ushortx8 a0 = *(const ushortx8*)&sP[(2 * w)     * 16 + l15][s * 32 + quad * 8];
      ushortx8 a1 = *(const ushortx8*)&sP[(2 * w + 1) * 16 + l15][s * 32 + quad * 8];
#pragma unroll
      for (int itl = 0; itl < 4; ++itl) {
        ushortx8 b = *(const ushortx8*)&sXT[itl * 16 + l15][s * 32 + quad * 8];
        hacc[0][itl] = mfma_bf16(a0, b, hacc[0][itl]);
        hacc[1][itl] = mfma_bf16(a1, b, hacc[1][itl]);
      }
    }
  }

  // ---- epilogue ----
  // D layout: i (cols) = itl*16 + l15, o (rows) = (2w+oi)*16 + quad*4 + e
  if (use_ws) {
    float* part = ws + (size_t)blockIdx.x * 8192;
#pragma unroll
    for (int oi = 0; oi < 2; ++oi)
#pragma unroll
      for (int itl = 0; itl < 4; ++itl)
#pragma unroll
        for (int e = 0; e < 4; ++e) {
          int o = (2 * w + oi) * 16 + quad * 4 + e;
          int i = itl * 16 + l15;
          part[o * 64 + i] = hacc[oi][itl][e];
        }
  } else {
#pragma unroll
    for (int oi = 0; oi < 2; ++oi)
#pragma unroll
      for (int itl = 0; itl < 4; ++itl)
#pragma unroll
        for (int e = 0; e < 4; ++e) {
          int o = (2 * w + oi) * 16 + quad * 4 + e;
          int i = itl * 16 + l15;
          atomicAdd(out + o * 64 + i, hacc[oi][itl][e]);
        }
  }
}

// sum 768 per-block partials -> out. 16384 threads, 2 atomics per element.
__global__ void reduce_kernel(const float* __restrict__ ws, float* __restrict__ out) {
  const int tid = blockIdx.x * 256 + threadIdx.x;  // 0..16383
  const int e = tid & 8191;
  const int half = tid >> 13;                      // 0 or 1
  const float* p = ws + (size_t)half * 384 * 8192 + e;
  float s = 0.f;
#pragma unroll 8
  for (int b = 0; b < 384; ++b) s += p[(size_t)b * 8192];
  atomicAdd(out + e, s);
}

__global__ void zero_out_kernel(float* out, int n) {
  int i = blockIdx.x * 256 + threadIdx.x;
  if (i < n) out[i] = 0.f;
}

extern "C" void kernel_launch(void* const* d_in, const int* in_sizes, int n_in,
                              void* d_out, int out_size, void* d_ws, size_t ws_size,
                              hipStream_t stream) {
  (void)in_sizes; (void)n_in;
  const float* x = (const float*)d_in[0];        // [524288, 64]
  const float* c = (const float*)d_in[1];        // [128, 64]
  float* out = (float*)d_out;                    // [128, 64]
  float* ws  = (float*)d_ws;

  const int use_ws = (ws_size >= (size_t)GRIDN * 8192 * sizeof(float)) ? 1 : 0;

  zero_out_kernel<<<(out_size + 255) / 256, 256, 0, stream>>>(out, out_size);
  rbf_hist_kernel<<<GRIDN, 256, 0, stream>>>(x, c, out, ws, use_ws);
  if (use_ws)
    reduce_kernel<<<64, 256, 0, stream>>>(ws, out);
}